// Round 1
// baseline (446.827 us; speedup 1.0000x reference)
//
#include <hip/hip_runtime.h>
#include <cstdint>

#define D_MODEL 1024
#define SEQ 2048
#define BATCH 8
#define M_TOTAL (BATCH*SEQ)   // 16384
#define NC 64                 // scan chunks per sequence
#define CL (SEQ/NC)           // 32 steps per chunk

typedef float f32x4 __attribute__((ext_vector_type(4)));
typedef short bf16x8 __attribute__((ext_vector_type(8)));

__device__ __forceinline__ float b2f(unsigned short s){
  union { float f; unsigned u; } z; z.u = ((unsigned)s) << 16; return z.f;
}
__device__ __forceinline__ unsigned short f2b(float f){
  union { float f; unsigned u; } z; z.f = f;
  unsigned u = z.u;
  u += 0x7fffu + ((u >> 16) & 1u);   // round-to-nearest-even
  return (unsigned short)(u >> 16);
}
__device__ __forceinline__ float sigmoidf_(float v){
  return 1.0f / (1.0f + __expf(-v));
}
__device__ __forceinline__ void gld_lds16(const void* g, void* l){
  __builtin_amdgcn_global_load_lds((const __attribute__((address_space(1))) unsigned int*)g,
                                   (__attribute__((address_space(3))) unsigned int*)l,
                                   16, 0, 0);
}

// ---------------- weight convert fp32 -> bf16 ----------------
__global__ __launch_bounds__(256) void wconv_kernel(const float* __restrict__ W0, const float* __restrict__ W1,
                                                    const float* __restrict__ W2, const float* __restrict__ W3,
                                                    unsigned short* __restrict__ WC){
  int mat = blockIdx.y;
  const float* src = (mat==0) ? W0 : (mat==1) ? W1 : (mat==2) ? W2 : W3;
  size_t i = ((size_t)blockIdx.x*256 + threadIdx.x)*4;
  float4 v = *(const float4*)(src + i);
  ushort4 o; o.x = f2b(v.x); o.y = f2b(v.y); o.z = f2b(v.z); o.w = f2b(v.w);
  *(ushort4*)(WC + (size_t)mat*1048576 + i) = o;
}

// ---------------- LayerNorm -> xn (bf16) ----------------
__global__ __launch_bounds__(256) void ln_kernel(const float* __restrict__ x, const float* __restrict__ lnw,
                                                 const float* __restrict__ lnb, unsigned short* __restrict__ xn){
  int m = blockIdx.x;
  int tid = threadIdx.x;
  const float4 xv = *(const float4*)(x + (size_t)m*D_MODEL + tid*4);
  float s1 = xv.x + xv.y + xv.z + xv.w;
  float s2 = xv.x*xv.x + xv.y*xv.y + xv.z*xv.z + xv.w*xv.w;
  #pragma unroll
  for (int off = 32; off > 0; off >>= 1){
    s1 += __shfl_xor(s1, off);
    s2 += __shfl_xor(s2, off);
  }
  __shared__ float r1[4], r2[4];
  int w = tid >> 6, lane = tid & 63;
  if (lane == 0){ r1[w] = s1; r2[w] = s2; }
  __syncthreads();
  s1 = r1[0] + r1[1] + r1[2] + r1[3];
  s2 = r2[0] + r2[1] + r2[2] + r2[3];
  float mean = s1 * (1.0f/1024.0f);
  float var  = s2 * (1.0f/1024.0f) - mean*mean;
  float rstd = rsqrtf(var + 1e-5f);
  float4 wv = *(const float4*)(lnw + tid*4);
  float4 bv = *(const float4*)(lnb + tid*4);
  ushort4 o;
  o.x = f2b((xv.x - mean)*rstd*wv.x + bv.x);
  o.y = f2b((xv.y - mean)*rstd*wv.y + bv.y);
  o.z = f2b((xv.z - mean)*rstd*wv.z + bv.z);
  o.w = f2b((xv.w - mean)*rstd*wv.w + bv.w);
  *(ushort4*)(xn + (size_t)m*D_MODEL + tid*4) = o;
}

// ---------------- GEMM with fused time-mix A-staging ----------------
// C[m][e] = sum_d ( tm[d]*xn[m][d] + (1-tm[d])*xn[m-1][d] ) * W[e][d]
// mode 0: store bf16   mode 1: multiply into existing (k -> k*v)   mode 2: sigmoid, store bf16
__global__ __launch_bounds__(256) void gemm_mix_kernel(const unsigned short* __restrict__ xn,
                                                       const unsigned short* __restrict__ W,
                                                       const float* __restrict__ tm,
                                                       unsigned short* __restrict__ outp,
                                                       int mode){
  int n0 = blockIdx.x * 128;
  int m0 = blockIdx.y * 128;
  int tid = threadIdx.x;

  __shared__ alignas(16) unsigned short As[128*64];
  __shared__ alignas(16) unsigned short Bs[128*64];

  f32x4 acc[4][4];
  #pragma unroll
  for (int i=0;i<4;i++)
    #pragma unroll
    for (int j=0;j<4;j++){ acc[i][j].x=0.f; acc[i][j].y=0.f; acc[i][j].z=0.f; acc[i][j].w=0.f; }

  int wid = tid >> 6, lane = tid & 63;
  int wm = wid >> 1, wn = wid & 1;
  int fr = lane & 15, fg = lane >> 4;

  for (int kt = 0; kt < D_MODEL; kt += 64){
    // stage: A via registers (mix), B via global_load_lds. Source is
    // column-pre-swizzled so that LDS position (row, cpos) holds global
    // chunk cpos ^ (row&7)  (both-sides-or-neither rule).
    #pragma unroll
    for (int it = 0; it < 4; ++it){
      int chunk = it*256 + tid;          // 0..1023
      int row = chunk >> 3;              // 0..127
      int cpos = chunk & 7;
      int cg = cpos ^ (row & 7);
      int dcol = kt + cg*8;
      int m = m0 + row;
      bf16x8 xt = *(const bf16x8*)(xn + (size_t)m*D_MODEL + dcol);
      bf16x8 xp = {0,0,0,0,0,0,0,0};
      if ((m & (SEQ-1)) != 0)
        xp = *(const bf16x8*)(xn + (size_t)(m-1)*D_MODEL + dcol);
      float tmv8[8];
      *(float4*)(&tmv8[0]) = *(const float4*)(tm + dcol);
      *(float4*)(&tmv8[4]) = *(const float4*)(tm + dcol + 4);
      bf16x8 o;
      #pragma unroll
      for (int j=0;j<8;j++){
        float u = b2f((unsigned short)xt[j]);
        float v = b2f((unsigned short)xp[j]);
        o[j] = (short)f2b(v + tmv8[j]*(u - v));   // tm*xn + (1-tm)*prev
      }
      *(bf16x8*)(&As[chunk*8]) = o;
      gld_lds16(W + (size_t)(n0+row)*D_MODEL + dcol, &Bs[chunk*8]);
    }
    __syncthreads();
    #pragma unroll
    for (int kp = 0; kp < 2; ++kp){
      int k8 = kp*4 + fg;
      bf16x8 a[4], b[4];
      #pragma unroll
      for (int mi=0; mi<4; ++mi){
        int r = wm*64 + mi*16 + fr;
        a[mi] = *(const bf16x8*)(&As[r*64 + ((k8 ^ (r & 7)) << 3)]);
      }
      #pragma unroll
      for (int ni=0; ni<4; ++ni){
        int r = wn*64 + ni*16 + fr;
        b[ni] = *(const bf16x8*)(&Bs[r*64 + ((k8 ^ (r & 7)) << 3)]);
      }
      #pragma unroll
      for (int mi=0; mi<4; ++mi)
        #pragma unroll
        for (int ni=0; ni<4; ++ni)
          acc[mi][ni] = __builtin_amdgcn_mfma_f32_16x16x32_bf16(a[mi], b[ni], acc[mi][ni], 0, 0, 0);
    }
    __syncthreads();
  }

  // epilogue: C/D layout col=lane&15, row=(lane>>4)*4+reg   [m89-verified]
  #pragma unroll
  for (int mi=0; mi<4; ++mi){
    #pragma unroll
    for (int ni=0; ni<4; ++ni){
      int c = n0 + wn*64 + ni*16 + fr;
      #pragma unroll
      for (int j=0; j<4; ++j){
        int r = m0 + wm*64 + mi*16 + fg*4 + j;
        size_t idx = (size_t)r*D_MODEL + c;
        float val = acc[mi][ni][j];
        if (mode == 2) val = sigmoidf_(val);
        if (mode == 1) val = val * b2f(outp[idx]);   // kv = v*k (k written by prior launch)
        outp[idx] = f2b(val);
      }
    }
  }
}

// ---------------- out GEMM: o = S_seq @ Wo^T ; out = x + r*o ----------------
__global__ __launch_bounds__(256) void gemm_out_kernel(const unsigned short* __restrict__ Sb,
                                                       const unsigned short* __restrict__ Wo,
                                                       const float* __restrict__ x,
                                                       const unsigned short* __restrict__ RB,
                                                       float* __restrict__ out){
  int n0 = blockIdx.x * 128;
  int m0 = blockIdx.y * 128;
  int tid = threadIdx.x;

  __shared__ alignas(16) unsigned short As[128*64];
  __shared__ alignas(16) unsigned short Bs[128*64];

  f32x4 acc[4][4];
  #pragma unroll
  for (int i=0;i<4;i++)
    #pragma unroll
    for (int j=0;j<4;j++){ acc[i][j].x=0.f; acc[i][j].y=0.f; acc[i][j].z=0.f; acc[i][j].w=0.f; }

  int wid = tid >> 6, lane = tid & 63;
  int wm = wid >> 1, wn = wid & 1;
  int fr = lane & 15, fg = lane >> 4;

  for (int kt = 0; kt < D_MODEL; kt += 64){
    #pragma unroll
    for (int it = 0; it < 4; ++it){
      int chunk = it*256 + tid;
      int row = chunk >> 3;
      int cpos = chunk & 7;
      int cg = cpos ^ (row & 7);
      int dcol = kt + cg*8;
      gld_lds16(Sb + (size_t)(m0+row)*D_MODEL + dcol, &As[chunk*8]);
      gld_lds16(Wo + (size_t)(n0+row)*D_MODEL + dcol, &Bs[chunk*8]);
    }
    __syncthreads();
    #pragma unroll
    for (int kp = 0; kp < 2; ++kp){
      int k8 = kp*4 + fg;
      bf16x8 a[4], b[4];
      #pragma unroll
      for (int mi=0; mi<4; ++mi){
        int r = wm*64 + mi*16 + fr;
        a[mi] = *(const bf16x8*)(&As[r*64 + ((k8 ^ (r & 7)) << 3)]);
      }
      #pragma unroll
      for (int ni=0; ni<4; ++ni){
        int r = wn*64 + ni*16 + fr;
        b[ni] = *(const bf16x8*)(&Bs[r*64 + ((k8 ^ (r & 7)) << 3)]);
      }
      #pragma unroll
      for (int mi=0; mi<4; ++mi)
        #pragma unroll
        for (int ni=0; ni<4; ++ni)
          acc[mi][ni] = __builtin_amdgcn_mfma_f32_16x16x32_bf16(a[mi], b[ni], acc[mi][ni], 0, 0, 0);
    }
    __syncthreads();
  }

  #pragma unroll
  for (int mi=0; mi<4; ++mi){
    #pragma unroll
    for (int ni=0; ni<4; ++ni){
      int c = n0 + wn*64 + ni*16 + fr;
      #pragma unroll
      for (int j=0; j<4; ++j){
        int r = m0 + wm*64 + mi*16 + fg*4 + j;
        size_t idx = (size_t)r*D_MODEL + c;
        float rr = b2f(RB[idx]);
        out[idx] = x[idx] + rr * acc[mi][ni][j];
      }
    }
  }
}

// ---------------- scan phase 1: per-chunk carries ----------------
__global__ __launch_bounds__(256) void scan_p1_kernel(const unsigned short* __restrict__ kv,
                                                      const float* __restrict__ dw,
                                                      float* __restrict__ carr){
  int bc = blockIdx.x;            // b*NC + c
  int b = bc >> 6, c = bc & (NC-1);
  int d0 = threadIdx.x * 4;
  float dx = sigmoidf_(dw[d0+0]);
  float dy = sigmoidf_(dw[d0+1]);
  float dz = sigmoidf_(dw[d0+2]);
  float dwv = sigmoidf_(dw[d0+3]);
  float Sx=0.f, Sy=0.f, Sz=0.f, Sw=0.f;
  size_t base = ((size_t)(b*SEQ + c*CL))*D_MODEL + d0;
  for (int i=0;i<CL;i++){
    ushort4 k4 = *(const ushort4*)(kv + base);
    Sx = dx*Sx + b2f(k4.x);
    Sy = dy*Sy + b2f(k4.y);
    Sz = dz*Sz + b2f(k4.z);
    Sw = dwv*Sw + b2f(k4.w);
    base += D_MODEL;
  }
  float4 o; o.x=Sx; o.y=Sy; o.z=Sz; o.w=Sw;
  *(float4*)(carr + (size_t)bc*D_MODEL + d0) = o;
}

// ---------------- scan phase 2: cross-chunk exclusive scan (in-place) ----------------
__global__ __launch_bounds__(256) void scan_p2_kernel(const float* __restrict__ dw, float* __restrict__ carr){
  int gid = blockIdx.x*256 + threadIdx.x;   // 0..8191
  int b = gid >> 10, d = gid & (D_MODEL-1);
  float dec = sigmoidf_(dw[d]);
  float dL = dec;
  #pragma unroll
  for (int i=0;i<5;i++) dL *= dL;           // dec^32
  float S = 0.f;
  for (int c=0;c<NC;c++){
    size_t idx = ((size_t)(b*NC + c))*D_MODEL + d;
    float cr = carr[idx];
    carr[idx] = S;                          // becomes carry-in
    S = dL*S + cr;
  }
}

// ---------------- scan phase 3: prefix with carry-in, write S_seq ----------------
__global__ __launch_bounds__(256) void scan_p3_kernel(const unsigned short* __restrict__ kv,
                                                      const float* __restrict__ dw,
                                                      const float* __restrict__ cin,
                                                      float* __restrict__ sseq,
                                                      float* __restrict__ finalS,
                                                      unsigned short* __restrict__ sb16){
  int bc = blockIdx.x;
  int b = bc >> 6, c = bc & (NC-1);
  int d0 = threadIdx.x * 4;
  float dx = sigmoidf_(dw[d0+0]);
  float dy = sigmoidf_(dw[d0+1]);
  float dz = sigmoidf_(dw[d0+2]);
  float dwv = sigmoidf_(dw[d0+3]);
  float4 S = *(const float4*)(cin + (size_t)bc*D_MODEL + d0);
  size_t base = ((size_t)(b*SEQ + c*CL))*D_MODEL + d0;
  for (int i=0;i<CL;i++){
    ushort4 k4 = *(const ushort4*)(kv + base);
    S.x = dx*S.x + b2f(k4.x);
    S.y = dy*S.y + b2f(k4.y);
    S.z = dz*S.z + b2f(k4.z);
    S.w = dwv*S.w + b2f(k4.w);
    *(float4*)(sseq + base) = S;
    ushort4 s4; s4.x = f2b(S.x); s4.y = f2b(S.y); s4.z = f2b(S.z); s4.w = f2b(S.w);
    *(ushort4*)(sb16 + base) = s4;
    base += D_MODEL;
  }
  if (c == NC-1)
    *(float4*)(finalS + (size_t)b*D_MODEL + d0) = S;
}

extern "C" void kernel_launch(void* const* d_in, const int* in_sizes, int n_in,
                              void* d_out, int out_size, void* d_ws, size_t ws_size,
                              hipStream_t stream){
  const float* x   = (const float*)d_in[0];
  const float* lnw = (const float*)d_in[1];
  const float* lnb = (const float*)d_in[2];
  const float* tmk = (const float*)d_in[3];
  const float* tmv = (const float*)d_in[4];
  const float* tmr = (const float*)d_in[5];
  const float* dw  = (const float*)d_in[6];
  const float* Wk  = (const float*)d_in[7];
  const float* Wv  = (const float*)d_in[8];
  const float* Wr  = (const float*)d_in[9];
  const float* Wo  = (const float*)d_in[10];

  float* out    = (float*)d_out;
  float* finalS = out + (size_t)M_TOTAL*D_MODEL;
  float* sseq   = finalS + (size_t)BATCH*D_MODEL;

  char* w = (char*)d_ws;
  unsigned short* XN   = (unsigned short*)(w + 0);           // 33.5 MB, reused as S_seq bf16
  unsigned short* WC   = (unsigned short*)(w + 33554432);    // 8.4 MB (Wk,Wv,Wr,Wo bf16)
  unsigned short* KB   = (unsigned short*)(w + 41943040);    // 33.5 MB: k, then k*v
  unsigned short* RB   = (unsigned short*)(w + 75497472);    // 33.5 MB: r = sigmoid(xr@Wr^T)
  float*          CARR = (float*)(w + 109051904);            // 2 MB carries (in-place -> carry-in)
  unsigned short* SB16 = XN;

  wconv_kernel<<<dim3(1024,4), 256, 0, stream>>>(Wk, Wv, Wr, Wo, WC);
  ln_kernel<<<M_TOTAL, 256, 0, stream>>>(x, lnw, lnb, XN);

  gemm_mix_kernel<<<dim3(8,128), 256, 0, stream>>>(XN, WC,                     tmk, KB, 0); // k
  gemm_mix_kernel<<<dim3(8,128), 256, 0, stream>>>(XN, WC + (size_t)1048576,   tmv, KB, 1); // kv = k*v
  gemm_mix_kernel<<<dim3(8,128), 256, 0, stream>>>(XN, WC + (size_t)2*1048576, tmr, RB, 2); // r

  scan_p1_kernel<<<BATCH*NC, 256, 0, stream>>>(KB, dw, CARR);
  scan_p2_kernel<<<32, 256, 0, stream>>>(dw, CARR);
  scan_p3_kernel<<<BATCH*NC, 256, 0, stream>>>(KB, dw, CARR, sseq, finalS, SB16);

  gemm_out_kernel<<<dim3(8,128), 256, 0, stream>>>(SB16, WC + (size_t)3*1048576, x, RB, out);
}

// Round 2
// 317.759 us; speedup vs baseline: 1.4062x; 1.4062x over previous
//
#include <hip/hip_runtime.h>
#include <cstdint>

#define D_MODEL 1024
#define SEQ 2048
#define BATCH 8
#define M_TOTAL (BATCH*SEQ)   // 16384
#define NC 64                 // scan chunks per sequence
#define CL (SEQ/NC)           // 32 steps per chunk

typedef float f32x4 __attribute__((ext_vector_type(4)));
typedef short bf16x8 __attribute__((ext_vector_type(8)));
typedef unsigned short u16x4 __attribute__((ext_vector_type(4)));

__device__ __forceinline__ float b2f(unsigned short s){
  union { float f; unsigned u; } z; z.u = ((unsigned)s) << 16; return z.f;
}
__device__ __forceinline__ unsigned short f2b(float f){
  union { float f; unsigned u; } z; z.f = f;
  unsigned u = z.u;
  u += 0x7fffu + ((u >> 16) & 1u);   // round-to-nearest-even
  return (unsigned short)(u >> 16);
}
__device__ __forceinline__ float sigmoidf_(float v){
  return 1.0f / (1.0f + __expf(-v));
}
__device__ __forceinline__ void gld_lds16(const void* g, void* l){
  __builtin_amdgcn_global_load_lds((const __attribute__((address_space(1))) unsigned int*)g,
                                   (__attribute__((address_space(3))) unsigned int*)l,
                                   16, 0, 0);
}

// ---------------- weight convert fp32 -> bf16 ----------------
__global__ __launch_bounds__(256) void wconv_kernel(const float* __restrict__ W0, const float* __restrict__ W1,
                                                    const float* __restrict__ W2, const float* __restrict__ W3,
                                                    unsigned short* __restrict__ WC){
  int mat = blockIdx.y;
  const float* src = (mat==0) ? W0 : (mat==1) ? W1 : (mat==2) ? W2 : W3;
  size_t i = ((size_t)blockIdx.x*256 + threadIdx.x)*4;
  f32x4 v = *(const f32x4*)(src + i);
  u16x4 o; o[0]=f2b(v[0]); o[1]=f2b(v[1]); o[2]=f2b(v[2]); o[3]=f2b(v[3]);
  *(u16x4*)(WC + (size_t)mat*1048576 + i) = o;
}

// ---------------- fused LayerNorm + time-mix -> xk, xv, xr (bf16) ----------------
// xn never materialized: each block LNs row m and row m-1 (dup compute, memory-bound anyway)
__global__ __launch_bounds__(256) void lnmix_kernel(const float* __restrict__ x,
                                                    const float* __restrict__ lnw, const float* __restrict__ lnb,
                                                    const float* __restrict__ tmk, const float* __restrict__ tmv,
                                                    const float* __restrict__ tmr,
                                                    unsigned short* __restrict__ XK, unsigned short* __restrict__ XV,
                                                    unsigned short* __restrict__ XR){
  int m = blockIdx.x;
  int tid = threadIdx.x;
  bool first = (m & (SEQ-1)) == 0;
  size_t base = (size_t)m*D_MODEL + tid*4;
  f32x4 xc = *(const f32x4*)(x + base);
  f32x4 xp = {0.f,0.f,0.f,0.f};
  if (!first) xp = *(const f32x4*)(x + base - D_MODEL);

  float c1 = xc[0]+xc[1]+xc[2]+xc[3];
  float c2 = xc[0]*xc[0]+xc[1]*xc[1]+xc[2]*xc[2]+xc[3]*xc[3];
  float p1 = xp[0]+xp[1]+xp[2]+xp[3];
  float p2 = xp[0]*xp[0]+xp[1]*xp[1]+xp[2]*xp[2]+xp[3]*xp[3];
  #pragma unroll
  for (int off = 32; off > 0; off >>= 1){
    c1 += __shfl_xor(c1, off); c2 += __shfl_xor(c2, off);
    p1 += __shfl_xor(p1, off); p2 += __shfl_xor(p2, off);
  }
  __shared__ float rc1[4], rc2[4], rp1[4], rp2[4];
  int w = tid >> 6, lane = tid & 63;
  if (lane == 0){ rc1[w]=c1; rc2[w]=c2; rp1[w]=p1; rp2[w]=p2; }
  __syncthreads();
  c1 = rc1[0]+rc1[1]+rc1[2]+rc1[3];
  c2 = rc2[0]+rc2[1]+rc2[2]+rc2[3];
  p1 = rp1[0]+rp1[1]+rp1[2]+rp1[3];
  p2 = rp2[0]+rp2[1]+rp2[2]+rp2[3];
  float mC = c1*(1.0f/1024.0f), vC = c2*(1.0f/1024.0f)-mC*mC, rC = rsqrtf(vC+1e-5f);
  float mP = p1*(1.0f/1024.0f), vP = p2*(1.0f/1024.0f)-mP*mP, rP = rsqrtf(vP+1e-5f);

  f32x4 wv = *(const f32x4*)(lnw + tid*4);
  f32x4 bv = *(const f32x4*)(lnb + tid*4);
  f32x4 k4 = *(const f32x4*)(tmk + tid*4);
  f32x4 v4 = *(const f32x4*)(tmv + tid*4);
  f32x4 r4 = *(const f32x4*)(tmr + tid*4);
  u16x4 ok, ov, orr;
  #pragma unroll
  for (int j=0;j<4;j++){
    float nc = (xc[j]-mC)*rC*wv[j] + bv[j];
    float np = first ? 0.f : (xp[j]-mP)*rP*wv[j] + bv[j];
    ok[j]  = f2b(np + k4[j]*(nc-np));
    ov[j]  = f2b(np + v4[j]*(nc-np));
    orr[j] = f2b(np + r4[j]*(nc-np));
  }
  *(u16x4*)(XK + base) = ok;
  *(u16x4*)(XV + base) = ov;
  *(u16x4*)(XR + base) = orr;
}

// ---------------- shared GEMM core: 128x128 tile, BK=64, gld_lds both operands ----------------
__device__ __forceinline__ void gemm_core(const unsigned short* __restrict__ A, const unsigned short* __restrict__ W,
                                          int m0, int n0, int tid,
                                          unsigned short* As, unsigned short* Bs,
                                          f32x4 (&acc)[4][4]){
  int wid = tid >> 6, lane = tid & 63;
  int wm = wid >> 1, wn = wid & 1;
  int fr = lane & 15, fg = lane >> 4;

  for (int kt = 0; kt < D_MODEL; kt += 64){
    #pragma unroll
    for (int it = 0; it < 4; ++it){
      int chunk = it*256 + tid;          // 0..1023
      int row = chunk >> 3;              // 0..127
      int cpos = chunk & 7;
      int cg = cpos ^ (row & 7);         // pre-swizzled source column group
      int dcol = kt + cg*8;
      gld_lds16(A + (size_t)(m0+row)*D_MODEL + dcol, &As[chunk*8]);
      gld_lds16(W + (size_t)(n0+row)*D_MODEL + dcol, &Bs[chunk*8]);
    }
    __syncthreads();
    #pragma unroll
    for (int kp = 0; kp < 2; ++kp){
      int k8 = kp*4 + fg;
      bf16x8 a[4], b[4];
      #pragma unroll
      for (int mi=0; mi<4; ++mi){
        int r = wm*64 + mi*16 + fr;
        a[mi] = *(const bf16x8*)(&As[r*64 + ((k8 ^ (r & 7)) << 3)]);
      }
      #pragma unroll
      for (int ni=0; ni<4; ++ni){
        int r = wn*64 + ni*16 + fr;
        b[ni] = *(const bf16x8*)(&Bs[r*64 + ((k8 ^ (r & 7)) << 3)]);
      }
      #pragma unroll
      for (int mi=0; mi<4; ++mi)
        #pragma unroll
        for (int ni=0; ni<4; ++ni)
          acc[mi][ni] = __builtin_amdgcn_mfma_f32_16x16x32_bf16(a[mi], b[ni], acc[mi][ni], 0, 0, 0);
    }
    __syncthreads();
  }
}

// ---------------- k and r GEMMs in one dispatch (z=0: k plain, z=1: r sigmoid) ----------------
__global__ __launch_bounds__(256) void gemm_kr_kernel(const unsigned short* __restrict__ XK,
                                                      const unsigned short* __restrict__ XR,
                                                      const unsigned short* __restrict__ Wk,
                                                      const unsigned short* __restrict__ Wr,
                                                      unsigned short* __restrict__ KB,
                                                      unsigned short* __restrict__ RB){
  int n0 = blockIdx.x * 128;
  int m0 = blockIdx.y * 128;
  int z  = blockIdx.z;
  int tid = threadIdx.x;
  __shared__ alignas(16) unsigned short As[128*64];
  __shared__ alignas(16) unsigned short Bs[128*64];
  f32x4 acc[4][4];
  #pragma unroll
  for (int i=0;i<4;i++)
    #pragma unroll
    for (int j=0;j<4;j++){ acc[i][j][0]=0.f; acc[i][j][1]=0.f; acc[i][j][2]=0.f; acc[i][j][3]=0.f; }

  const unsigned short* A = z ? XR : XK;
  const unsigned short* W = z ? Wr : Wk;
  unsigned short* O       = z ? RB : KB;
  gemm_core(A, W, m0, n0, tid, As, Bs, acc);

  int wid = tid >> 6, lane = tid & 63;
  int wm = wid >> 1, wn = wid & 1;
  int fr = lane & 15, fg = lane >> 4;
  #pragma unroll
  for (int mi=0; mi<4; ++mi){
    #pragma unroll
    for (int ni=0; ni<4; ++ni){
      int c = n0 + wn*64 + ni*16 + fr;
      #pragma unroll
      for (int j=0; j<4; ++j){
        int r = m0 + wm*64 + mi*16 + fg*4 + j;
        size_t idx = (size_t)r*D_MODEL + c;
        float val = acc[mi][ni][j];
        if (z) val = sigmoidf_(val);
        O[idx] = f2b(val);
      }
    }
  }
}

// ---------------- v GEMM: kv = v * k (RMW into KB, k written by prior dispatch) ----------------
__global__ __launch_bounds__(256) void gemm_v_kernel(const unsigned short* __restrict__ XV,
                                                     const unsigned short* __restrict__ Wv,
                                                     unsigned short* __restrict__ KB){
  int n0 = blockIdx.x * 128;
  int m0 = blockIdx.y * 128;
  int tid = threadIdx.x;
  __shared__ alignas(16) unsigned short As[128*64];
  __shared__ alignas(16) unsigned short Bs[128*64];
  f32x4 acc[4][4];
  #pragma unroll
  for (int i=0;i<4;i++)
    #pragma unroll
    for (int j=0;j<4;j++){ acc[i][j][0]=0.f; acc[i][j][1]=0.f; acc[i][j][2]=0.f; acc[i][j][3]=0.f; }

  gemm_core(XV, Wv, m0, n0, tid, As, Bs, acc);

  int wid = tid >> 6, lane = tid & 63;
  int wm = wid >> 1, wn = wid & 1;
  int fr = lane & 15, fg = lane >> 4;
  #pragma unroll
  for (int mi=0; mi<4; ++mi){
    #pragma unroll
    for (int ni=0; ni<4; ++ni){
      int c = n0 + wn*64 + ni*16 + fr;
      #pragma unroll
      for (int j=0; j<4; ++j){
        int r = m0 + wm*64 + mi*16 + fg*4 + j;
        size_t idx = (size_t)r*D_MODEL + c;
        KB[idx] = f2b(acc[mi][ni][j] * b2f(KB[idx]));
      }
    }
  }
}

// ---------------- out GEMM: o = S_seq @ Wo^T ; out = x + r*o ----------------
__global__ __launch_bounds__(256) void gemm_out_kernel(const unsigned short* __restrict__ Sb,
                                                       const unsigned short* __restrict__ Wo,
                                                       const float* __restrict__ x,
                                                       const unsigned short* __restrict__ RB,
                                                       float* __restrict__ out){
  int n0 = blockIdx.x * 128;
  int m0 = blockIdx.y * 128;
  int tid = threadIdx.x;
  __shared__ alignas(16) unsigned short As[128*64];
  __shared__ alignas(16) unsigned short Bs[128*64];
  f32x4 acc[4][4];
  #pragma unroll
  for (int i=0;i<4;i++)
    #pragma unroll
    for (int j=0;j<4;j++){ acc[i][j][0]=0.f; acc[i][j][1]=0.f; acc[i][j][2]=0.f; acc[i][j][3]=0.f; }

  gemm_core(Sb, Wo, m0, n0, tid, As, Bs, acc);

  int wid = tid >> 6, lane = tid & 63;
  int wm = wid >> 1, wn = wid & 1;
  int fr = lane & 15, fg = lane >> 4;
  #pragma unroll
  for (int mi=0; mi<4; ++mi){
    #pragma unroll
    for (int ni=0; ni<4; ++ni){
      int c = n0 + wn*64 + ni*16 + fr;
      #pragma unroll
      for (int j=0; j<4; ++j){
        int r = m0 + wm*64 + mi*16 + fg*4 + j;
        size_t idx = (size_t)r*D_MODEL + c;
        float rr = b2f(RB[idx]);
        out[idx] = x[idx] + rr * acc[mi][ni][j];
      }
    }
  }
}

// ---------------- scan phase 1: per-chunk carries ----------------
__global__ __launch_bounds__(256) void scan_p1_kernel(const unsigned short* __restrict__ kv,
                                                      const float* __restrict__ dw,
                                                      float* __restrict__ carr){
  int bc = blockIdx.x;            // b*NC + c
  int b = bc >> 6, c = bc & (NC-1);
  int d0 = threadIdx.x * 4;
  float dx = sigmoidf_(dw[d0+0]);
  float dy = sigmoidf_(dw[d0+1]);
  float dz = sigmoidf_(dw[d0+2]);
  float dwv = sigmoidf_(dw[d0+3]);
  float Sx=0.f, Sy=0.f, Sz=0.f, Sw=0.f;
  size_t base = ((size_t)(b*SEQ + c*CL))*D_MODEL + d0;
  for (int i=0;i<CL;i++){
    u16x4 k4 = *(const u16x4*)(kv + base);
    Sx = dx*Sx + b2f(k4[0]);
    Sy = dy*Sy + b2f(k4[1]);
    Sz = dz*Sz + b2f(k4[2]);
    Sw = dwv*Sw + b2f(k4[3]);
    base += D_MODEL;
  }
  f32x4 o; o[0]=Sx; o[1]=Sy; o[2]=Sz; o[3]=Sw;
  *(f32x4*)(carr + (size_t)bc*D_MODEL + d0) = o;
}

// ---------------- scan phase 2: cross-chunk exclusive scan (in-place) ----------------
__global__ __launch_bounds__(256) void scan_p2_kernel(const float* __restrict__ dw, float* __restrict__ carr){
  int gid = blockIdx.x*256 + threadIdx.x;   // 0..8191
  int b = gid >> 10, d = gid & (D_MODEL-1);
  float dec = sigmoidf_(dw[d]);
  float dL = dec;
  #pragma unroll
  for (int i=0;i<5;i++) dL *= dL;           // dec^32
  float S = 0.f;
  for (int c=0;c<NC;c++){
    size_t idx = ((size_t)(b*NC + c))*D_MODEL + d;
    float cr = carr[idx];
    carr[idx] = S;                          // becomes carry-in
    S = dL*S + cr;
  }
}

// ---------------- scan phase 3: prefix with carry-in, write S_seq ----------------
__global__ __launch_bounds__(256) void scan_p3_kernel(const unsigned short* __restrict__ kv,
                                                      const float* __restrict__ dw,
                                                      const float* __restrict__ cin,
                                                      float* __restrict__ sseq,
                                                      float* __restrict__ finalS,
                                                      unsigned short* __restrict__ sb16){
  int bc = blockIdx.x;
  int b = bc >> 6, c = bc & (NC-1);
  int d0 = threadIdx.x * 4;
  float dx = sigmoidf_(dw[d0+0]);
  float dy = sigmoidf_(dw[d0+1]);
  float dz = sigmoidf_(dw[d0+2]);
  float dwv = sigmoidf_(dw[d0+3]);
  f32x4 S = *(const f32x4*)(cin + (size_t)bc*D_MODEL + d0);
  size_t base = ((size_t)(b*SEQ + c*CL))*D_MODEL + d0;
  for (int i=0;i<CL;i++){
    u16x4 k4 = *(const u16x4*)(kv + base);
    S[0] = dx*S[0] + b2f(k4[0]);
    S[1] = dy*S[1] + b2f(k4[1]);
    S[2] = dz*S[2] + b2f(k4[2]);
    S[3] = dwv*S[3] + b2f(k4[3]);
    *(f32x4*)(sseq + base) = S;
    u16x4 s4; s4[0]=f2b(S[0]); s4[1]=f2b(S[1]); s4[2]=f2b(S[2]); s4[3]=f2b(S[3]);
    *(u16x4*)(sb16 + base) = s4;
    base += D_MODEL;
  }
  if (c == NC-1)
    *(f32x4*)(finalS + (size_t)b*D_MODEL + d0) = S;
}

extern "C" void kernel_launch(void* const* d_in, const int* in_sizes, int n_in,
                              void* d_out, int out_size, void* d_ws, size_t ws_size,
                              hipStream_t stream){
  const float* x   = (const float*)d_in[0];
  const float* lnw = (const float*)d_in[1];
  const float* lnb = (const float*)d_in[2];
  const float* tmk = (const float*)d_in[3];
  const float* tmv = (const float*)d_in[4];
  const float* tmr = (const float*)d_in[5];
  const float* dw  = (const float*)d_in[6];
  const float* Wk  = (const float*)d_in[7];
  const float* Wv  = (const float*)d_in[8];
  const float* Wr  = (const float*)d_in[9];
  const float* Wo  = (const float*)d_in[10];

  float* out    = (float*)d_out;
  float* finalS = out + (size_t)M_TOTAL*D_MODEL;
  float* sseq   = finalS + (size_t)BATCH*D_MODEL;

  // d_out doubles as GEMM-phase scratch:
  //   XK = out[0 .. 33.5MB)          dead before gemm_out writes out
  //   XV = out[33.5MB .. 67.1MB)     dead before gemm_out writes out
  //   XR = sseq region (first 33.5MB) dead before scan_p3 writes sseq
  unsigned short* XK = (unsigned short*)d_out;
  unsigned short* XV = (unsigned short*)((char*)d_out + 33554432);
  unsigned short* XR = (unsigned short*)sseq;

  char* w = (char*)d_ws;
  unsigned short* WC   = (unsigned short*)(w + 0);           // 8.4 MB (Wk,Wv,Wr,Wo bf16)
  unsigned short* SB16 = (unsigned short*)(w + 8388608);     // 33.5 MB: S_seq bf16 for out-GEMM
  unsigned short* KB   = (unsigned short*)(w + 41943040);    // 33.5 MB: k, then k*v
  unsigned short* RB   = (unsigned short*)(w + 75497472);    // 33.5 MB: r = sigmoid(xr@Wr^T)
  float*          CARR = (float*)(w + 109051904);            // 2 MB carries (in-place -> carry-in)

  wconv_kernel<<<dim3(1024,4), 256, 0, stream>>>(Wk, Wv, Wr, Wo, WC);
  lnmix_kernel<<<M_TOTAL, 256, 0, stream>>>(x, lnw, lnb, tmk, tmv, tmr, XK, XV, XR);

  gemm_kr_kernel<<<dim3(8,128,2), 256, 0, stream>>>(XK, XR, WC, WC + (size_t)2*1048576, KB, RB);
  gemm_v_kernel<<<dim3(8,128), 256, 0, stream>>>(XV, WC + (size_t)1048576, KB);

  scan_p1_kernel<<<BATCH*NC, 256, 0, stream>>>(KB, dw, CARR);
  scan_p2_kernel<<<32, 256, 0, stream>>>(dw, CARR);
  scan_p3_kernel<<<BATCH*NC, 256, 0, stream>>>(KB, dw, CARR, sseq, finalS, SB16);

  gemm_out_kernel<<<dim3(8,128), 256, 0, stream>>>(SB16, WC + (size_t)3*1048576, x, RB, out);
}

// Round 3
// 297.313 us; speedup vs baseline: 1.5029x; 1.0688x over previous
//
#include <hip/hip_runtime.h>
#include <cstdint>

#define D_MODEL 1024
#define SEQ 2048
#define BATCH 8
#define M_TOTAL (BATCH*SEQ)   // 16384
#define NC 64                 // scan chunks per sequence
#define CL (SEQ/NC)           // 32 steps per chunk

typedef float f32x4 __attribute__((ext_vector_type(4)));
typedef short bf16x8 __attribute__((ext_vector_type(8)));
typedef unsigned short u16x4 __attribute__((ext_vector_type(4)));

__device__ __forceinline__ float b2f(unsigned short s){
  union { float f; unsigned u; } z; z.u = ((unsigned)s) << 16; return z.f;
}
__device__ __forceinline__ unsigned short f2b(float f){
  union { float f; unsigned u; } z; z.f = f;
  unsigned u = z.u;
  u += 0x7fffu + ((u >> 16) & 1u);   // round-to-nearest-even
  return (unsigned short)(u >> 16);
}
__device__ __forceinline__ float sigmoidf_(float v){
  return 1.0f / (1.0f + __expf(-v));
}
__device__ __forceinline__ void gld_lds16(const void* g, void* l){
  __builtin_amdgcn_global_load_lds((const __attribute__((address_space(1))) unsigned int*)g,
                                   (__attribute__((address_space(3))) unsigned int*)l,
                                   16, 0, 0);
}

// XCD-chunked swizzle: 1024-block GEMM grid (128 m-panels x 8 n-panels).
// Each XCD owns 16 consecutive m-panels; within an XCD consecutive blocks
// cover the 8 n-panels of one m-panel -> A-panel fetched once, working set
// ~2MB A + 2MB B = one XCD L2. [T1, m192/m204]
__device__ __forceinline__ void swz_mn(int bid, int& m0, int& n0){
  int xcd = bid & 7;
  int loc = bid >> 3;              // 0..127
  int wg  = xcd*128 + loc;         // contiguous chunk per XCD
  m0 = (wg >> 3) * 128;
  n0 = (wg & 7) * 128;
}

// ---------------- weight convert fp32 -> bf16 ----------------
__global__ __launch_bounds__(256) void wconv_kernel(const float* __restrict__ W0, const float* __restrict__ W1,
                                                    const float* __restrict__ W2, const float* __restrict__ W3,
                                                    unsigned short* __restrict__ WC){
  int mat = blockIdx.y;
  const float* src = (mat==0) ? W0 : (mat==1) ? W1 : (mat==2) ? W2 : W3;
  size_t i = ((size_t)blockIdx.x*256 + threadIdx.x)*4;
  f32x4 v = *(const f32x4*)(src + i);
  u16x4 o; o[0]=f2b(v[0]); o[1]=f2b(v[1]); o[2]=f2b(v[2]); o[3]=f2b(v[3]);
  *(u16x4*)(WC + (size_t)mat*1048576 + i) = o;
}

// ---------------- fused LayerNorm + time-mix -> xk, xv, xr (bf16) ----------------
__global__ __launch_bounds__(256) void lnmix_kernel(const float* __restrict__ x,
                                                    const float* __restrict__ lnw, const float* __restrict__ lnb,
                                                    const float* __restrict__ tmk, const float* __restrict__ tmv,
                                                    const float* __restrict__ tmr,
                                                    unsigned short* __restrict__ XK, unsigned short* __restrict__ XV,
                                                    unsigned short* __restrict__ XR){
  int m = blockIdx.x;
  int tid = threadIdx.x;
  bool first = (m & (SEQ-1)) == 0;
  size_t base = (size_t)m*D_MODEL + tid*4;
  f32x4 xc = *(const f32x4*)(x + base);
  f32x4 xp = {0.f,0.f,0.f,0.f};
  if (!first) xp = *(const f32x4*)(x + base - D_MODEL);

  float c1 = xc[0]+xc[1]+xc[2]+xc[3];
  float c2 = xc[0]*xc[0]+xc[1]*xc[1]+xc[2]*xc[2]+xc[3]*xc[3];
  float p1 = xp[0]+xp[1]+xp[2]+xp[3];
  float p2 = xp[0]*xp[0]+xp[1]*xp[1]+xp[2]*xp[2]+xp[3]*xp[3];
  #pragma unroll
  for (int off = 32; off > 0; off >>= 1){
    c1 += __shfl_xor(c1, off); c2 += __shfl_xor(c2, off);
    p1 += __shfl_xor(p1, off); p2 += __shfl_xor(p2, off);
  }
  __shared__ float rc1[4], rc2[4], rp1[4], rp2[4];
  int w = tid >> 6, lane = tid & 63;
  if (lane == 0){ rc1[w]=c1; rc2[w]=c2; rp1[w]=p1; rp2[w]=p2; }
  __syncthreads();
  c1 = rc1[0]+rc1[1]+rc1[2]+rc1[3];
  c2 = rc2[0]+rc2[1]+rc2[2]+rc2[3];
  p1 = rp1[0]+rp1[1]+rp1[2]+rp1[3];
  p2 = rp2[0]+rp2[1]+rp2[2]+rp2[3];
  float mC = c1*(1.0f/1024.0f), vC = c2*(1.0f/1024.0f)-mC*mC, rC = rsqrtf(vC+1e-5f);
  float mP = p1*(1.0f/1024.0f), vP = p2*(1.0f/1024.0f)-mP*mP, rP = rsqrtf(vP+1e-5f);

  f32x4 wv = *(const f32x4*)(lnw + tid*4);
  f32x4 bv = *(const f32x4*)(lnb + tid*4);
  f32x4 k4 = *(const f32x4*)(tmk + tid*4);
  f32x4 v4 = *(const f32x4*)(tmv + tid*4);
  f32x4 r4 = *(const f32x4*)(tmr + tid*4);
  u16x4 ok, ov, orr;
  #pragma unroll
  for (int j=0;j<4;j++){
    float nc = (xc[j]-mC)*rC*wv[j] + bv[j];
    float np = first ? 0.f : (xp[j]-mP)*rP*wv[j] + bv[j];
    ok[j]  = f2b(np + k4[j]*(nc-np));
    ov[j]  = f2b(np + v4[j]*(nc-np));
    orr[j] = f2b(np + r4[j]*(nc-np));
  }
  *(u16x4*)(XK + base) = ok;
  *(u16x4*)(XV + base) = ov;
  *(u16x4*)(XR + base) = orr;
}

// ---------------- shared GEMM core: 128x128 tile, BK=64, gld_lds both operands ----------------
__device__ __forceinline__ void gemm_core(const unsigned short* __restrict__ A, const unsigned short* __restrict__ W,
                                          int m0, int n0, int tid,
                                          unsigned short* As, unsigned short* Bs,
                                          f32x4 (&acc)[4][4]){
  int wid = tid >> 6, lane = tid & 63;
  int wm = wid >> 1, wn = wid & 1;
  int fr = lane & 15, fg = lane >> 4;

  for (int kt = 0; kt < D_MODEL; kt += 64){
    #pragma unroll
    for (int it = 0; it < 4; ++it){
      int chunk = it*256 + tid;          // 0..1023
      int row = chunk >> 3;              // 0..127
      int cpos = chunk & 7;
      int cg = cpos ^ (row & 7);         // pre-swizzled source column group
      int dcol = kt + cg*8;
      gld_lds16(A + (size_t)(m0+row)*D_MODEL + dcol, &As[chunk*8]);
      gld_lds16(W + (size_t)(n0+row)*D_MODEL + dcol, &Bs[chunk*8]);
    }
    __syncthreads();
    #pragma unroll
    for (int kp = 0; kp < 2; ++kp){
      int k8 = kp*4 + fg;
      bf16x8 a[4], b[4];
      #pragma unroll
      for (int mi=0; mi<4; ++mi){
        int r = wm*64 + mi*16 + fr;
        a[mi] = *(const bf16x8*)(&As[r*64 + ((k8 ^ (r & 7)) << 3)]);
      }
      #pragma unroll
      for (int ni=0; ni<4; ++ni){
        int r = wn*64 + ni*16 + fr;
        b[ni] = *(const bf16x8*)(&Bs[r*64 + ((k8 ^ (r & 7)) << 3)]);
      }
      #pragma unroll
      for (int mi=0; mi<4; ++mi)
        #pragma unroll
        for (int ni=0; ni<4; ++ni)
          acc[mi][ni] = __builtin_amdgcn_mfma_f32_16x16x32_bf16(a[mi], b[ni], acc[mi][ni], 0, 0, 0);
    }
    __syncthreads();
  }
}

// ---------------- k and r GEMMs in one dispatch (z=0: k plain, z=1: r sigmoid) ----------------
__global__ __launch_bounds__(256) void gemm_kr_kernel(const unsigned short* __restrict__ XK,
                                                      const unsigned short* __restrict__ XR,
                                                      const unsigned short* __restrict__ Wk,
                                                      const unsigned short* __restrict__ Wr,
                                                      unsigned short* __restrict__ KB,
                                                      unsigned short* __restrict__ RB){
  int m0, n0;
  swz_mn(blockIdx.x, m0, n0);
  int z  = blockIdx.z;
  int tid = threadIdx.x;
  __shared__ alignas(16) unsigned short As[128*64];
  __shared__ alignas(16) unsigned short Bs[128*64];
  f32x4 acc[4][4];
  #pragma unroll
  for (int i=0;i<4;i++)
    #pragma unroll
    for (int j=0;j<4;j++){ acc[i][j][0]=0.f; acc[i][j][1]=0.f; acc[i][j][2]=0.f; acc[i][j][3]=0.f; }

  const unsigned short* A = z ? XR : XK;
  const unsigned short* W = z ? Wr : Wk;
  unsigned short* O       = z ? RB : KB;
  gemm_core(A, W, m0, n0, tid, As, Bs, acc);

  int wid = tid >> 6, lane = tid & 63;
  int wm = wid >> 1, wn = wid & 1;
  int fr = lane & 15, fg = lane >> 4;
  #pragma unroll
  for (int mi=0; mi<4; ++mi){
    #pragma unroll
    for (int ni=0; ni<4; ++ni){
      int c = n0 + wn*64 + ni*16 + fr;
      #pragma unroll
      for (int j=0; j<4; ++j){
        int r = m0 + wm*64 + mi*16 + fg*4 + j;
        size_t idx = (size_t)r*D_MODEL + c;
        float val = acc[mi][ni][j];
        if (z) val = sigmoidf_(val);
        O[idx] = f2b(val);
      }
    }
  }
}

// ---------------- v GEMM: kv = v * k (RMW into KB, k written by prior dispatch) ----------------
__global__ __launch_bounds__(256) void gemm_v_kernel(const unsigned short* __restrict__ XV,
                                                     const unsigned short* __restrict__ Wv,
                                                     unsigned short* __restrict__ KB){
  int m0, n0;
  swz_mn(blockIdx.x, m0, n0);
  int tid = threadIdx.x;
  __shared__ alignas(16) unsigned short As[128*64];
  __shared__ alignas(16) unsigned short Bs[128*64];
  f32x4 acc[4][4];
  #pragma unroll
  for (int i=0;i<4;i++)
    #pragma unroll
    for (int j=0;j<4;j++){ acc[i][j][0]=0.f; acc[i][j][1]=0.f; acc[i][j][2]=0.f; acc[i][j][3]=0.f; }

  gemm_core(XV, Wv, m0, n0, tid, As, Bs, acc);

  int wid = tid >> 6, lane = tid & 63;
  int wm = wid >> 1, wn = wid & 1;
  int fr = lane & 15, fg = lane >> 4;
  #pragma unroll
  for (int mi=0; mi<4; ++mi){
    #pragma unroll
    for (int ni=0; ni<4; ++ni){
      int c = n0 + wn*64 + ni*16 + fr;
      #pragma unroll
      for (int j=0; j<4; ++j){
        int r = m0 + wm*64 + mi*16 + fg*4 + j;
        size_t idx = (size_t)r*D_MODEL + c;
        KB[idx] = f2b(acc[mi][ni][j] * b2f(KB[idx]));
      }
    }
  }
}

// ---------------- out GEMM: o = S_seq @ Wo^T ; out = x + r*o ----------------
__global__ __launch_bounds__(256) void gemm_out_kernel(const unsigned short* __restrict__ Sb,
                                                       const unsigned short* __restrict__ Wo,
                                                       const float* __restrict__ x,
                                                       const unsigned short* __restrict__ RB,
                                                       float* __restrict__ out){
  int m0, n0;
  swz_mn(blockIdx.x, m0, n0);
  int tid = threadIdx.x;
  __shared__ alignas(16) unsigned short As[128*64];
  __shared__ alignas(16) unsigned short Bs[128*64];
  f32x4 acc[4][4];
  #pragma unroll
  for (int i=0;i<4;i++)
    #pragma unroll
    for (int j=0;j<4;j++){ acc[i][j][0]=0.f; acc[i][j][1]=0.f; acc[i][j][2]=0.f; acc[i][j][3]=0.f; }

  gemm_core(Sb, Wo, m0, n0, tid, As, Bs, acc);

  int wid = tid >> 6, lane = tid & 63;
  int wm = wid >> 1, wn = wid & 1;
  int fr = lane & 15, fg = lane >> 4;
  #pragma unroll
  for (int mi=0; mi<4; ++mi){
    #pragma unroll
    for (int ni=0; ni<4; ++ni){
      int c = n0 + wn*64 + ni*16 + fr;
      #pragma unroll
      for (int j=0; j<4; ++j){
        int r = m0 + wm*64 + mi*16 + fg*4 + j;
        size_t idx = (size_t)r*D_MODEL + c;
        float rr = b2f(RB[idx]);
        out[idx] = x[idx] + rr * acc[mi][ni][j];
      }
    }
  }
}

// ---------------- scan phase 1: per-chunk carries ----------------
__global__ __launch_bounds__(256) void scan_p1_kernel(const unsigned short* __restrict__ kv,
                                                      const float* __restrict__ dw,
                                                      float* __restrict__ carr){
  int bc = blockIdx.x;            // b*NC + c
  int b = bc >> 6, c = bc & (NC-1);
  int d0 = threadIdx.x * 4;
  float dx = sigmoidf_(dw[d0+0]);
  float dy = sigmoidf_(dw[d0+1]);
  float dz = sigmoidf_(dw[d0+2]);
  float dwv = sigmoidf_(dw[d0+3]);
  float Sx=0.f, Sy=0.f, Sz=0.f, Sw=0.f;
  size_t base = ((size_t)(b*SEQ + c*CL))*D_MODEL + d0;
  for (int i=0;i<CL;i++){
    u16x4 k4 = *(const u16x4*)(kv + base);
    Sx = dx*Sx + b2f(k4[0]);
    Sy = dy*Sy + b2f(k4[1]);
    Sz = dz*Sz + b2f(k4[2]);
    Sw = dwv*Sw + b2f(k4[3]);
    base += D_MODEL;
  }
  f32x4 o; o[0]=Sx; o[1]=Sy; o[2]=Sz; o[3]=Sw;
  *(f32x4*)(carr + (size_t)bc*D_MODEL + d0) = o;
}

// ---------------- scan phase 2: cross-chunk exclusive scan (in-place) ----------------
__global__ __launch_bounds__(256) void scan_p2_kernel(const float* __restrict__ dw, float* __restrict__ carr){
  int gid = blockIdx.x*256 + threadIdx.x;   // 0..8191
  int b = gid >> 10, d = gid & (D_MODEL-1);
  float dec = sigmoidf_(dw[d]);
  float dL = dec;
  #pragma unroll
  for (int i=0;i<5;i++) dL *= dL;           // dec^32
  float S = 0.f;
  for (int c=0;c<NC;c++){
    size_t idx = ((size_t)(b*NC + c))*D_MODEL + d;
    float cr = carr[idx];
    carr[idx] = S;                          // becomes carry-in
    S = dL*S + cr;
  }
}

// ---------------- scan phase 3: prefix with carry-in, write S_seq ----------------
__global__ __launch_bounds__(256) void scan_p3_kernel(const unsigned short* __restrict__ kv,
                                                      const float* __restrict__ dw,
                                                      const float* __restrict__ cin,
                                                      float* __restrict__ sseq,
                                                      float* __restrict__ finalS,
                                                      unsigned short* __restrict__ sb16){
  int bc = blockIdx.x;
  int b = bc >> 6, c = bc & (NC-1);
  int d0 = threadIdx.x * 4;
  float dx = sigmoidf_(dw[d0+0]);
  float dy = sigmoidf_(dw[d0+1]);
  float dz = sigmoidf_(dw[d0+2]);
  float dwv = sigmoidf_(dw[d0+3]);
  f32x4 S = *(const f32x4*)(cin + (size_t)bc*D_MODEL + d0);
  size_t base = ((size_t)(b*SEQ + c*CL))*D_MODEL + d0;
  for (int i=0;i<CL;i++){
    u16x4 k4 = *(const u16x4*)(kv + base);
    S[0] = dx*S[0] + b2f(k4[0]);
    S[1] = dy*S[1] + b2f(k4[1]);
    S[2] = dz*S[2] + b2f(k4[2]);
    S[3] = dwv*S[3] + b2f(k4[3]);
    *(f32x4*)(sseq + base) = S;
    u16x4 s4; s4[0]=f2b(S[0]); s4[1]=f2b(S[1]); s4[2]=f2b(S[2]); s4[3]=f2b(S[3]);
    *(u16x4*)(sb16 + base) = s4;
    base += D_MODEL;
  }
  if (c == NC-1)
    *(f32x4*)(finalS + (size_t)b*D_MODEL + d0) = S;
}

extern "C" void kernel_launch(void* const* d_in, const int* in_sizes, int n_in,
                              void* d_out, int out_size, void* d_ws, size_t ws_size,
                              hipStream_t stream){
  const float* x   = (const float*)d_in[0];
  const float* lnw = (const float*)d_in[1];
  const float* lnb = (const float*)d_in[2];
  const float* tmk = (const float*)d_in[3];
  const float* tmv = (const float*)d_in[4];
  const float* tmr = (const float*)d_in[5];
  const float* dw  = (const float*)d_in[6];
  const float* Wk  = (const float*)d_in[7];
  const float* Wv  = (const float*)d_in[8];
  const float* Wr  = (const float*)d_in[9];
  const float* Wo  = (const float*)d_in[10];

  float* out    = (float*)d_out;
  float* finalS = out + (size_t)M_TOTAL*D_MODEL;
  float* sseq   = finalS + (size_t)BATCH*D_MODEL;

  // d_out doubles as GEMM-phase scratch:
  //   XK = out[0 .. 33.5MB)          dead before gemm_out writes out
  //   XV = out[33.5MB .. 67.1MB)     dead before gemm_out writes out
  //   XR = sseq region (first 33.5MB) dead before scan_p3 writes sseq
  unsigned short* XK = (unsigned short*)d_out;
  unsigned short* XV = (unsigned short*)((char*)d_out + 33554432);
  unsigned short* XR = (unsigned short*)sseq;

  char* w = (char*)d_ws;
  unsigned short* WC   = (unsigned short*)(w + 0);           // 8.4 MB (Wk,Wv,Wr,Wo bf16)
  unsigned short* SB16 = (unsigned short*)(w + 8388608);     // 33.5 MB: S_seq bf16 for out-GEMM
  unsigned short* KB   = (unsigned short*)(w + 41943040);    // 33.5 MB: k, then k*v
  unsigned short* RB   = (unsigned short*)(w + 75497472);    // 33.5 MB: r = sigmoid(xr@Wr^T)
  float*          CARR = (float*)(w + 109051904);            // 2 MB carries (in-place -> carry-in)

  wconv_kernel<<<dim3(1024,4), 256, 0, stream>>>(Wk, Wv, Wr, Wo, WC);
  lnmix_kernel<<<M_TOTAL, 256, 0, stream>>>(x, lnw, lnb, tmk, tmv, tmr, XK, XV, XR);

  gemm_kr_kernel<<<dim3(1024,1,2), 256, 0, stream>>>(XK, XR, WC, WC + (size_t)2*1048576, KB, RB);
  gemm_v_kernel<<<1024, 256, 0, stream>>>(XV, WC + (size_t)1048576, KB);

  scan_p1_kernel<<<BATCH*NC, 256, 0, stream>>>(KB, dw, CARR);
  scan_p2_kernel<<<32, 256, 0, stream>>>(dw, CARR);
  scan_p3_kernel<<<BATCH*NC, 256, 0, stream>>>(KB, dw, CARR, sseq, finalS, SB16);

  gemm_out_kernel<<<1024, 256, 0, stream>>>(SB16, WC + (size_t)3*1048576, x, RB, out);
}

// Round 4
// 287.814 us; speedup vs baseline: 1.5525x; 1.0330x over previous
//
#include <hip/hip_runtime.h>
#include <cstdint>

#define D_MODEL 1024
#define SEQ 2048
#define BATCH 8
#define M_TOTAL (BATCH*SEQ)   // 16384
#define NC 64                 // scan chunks per sequence
#define CL (SEQ/NC)           // 32 steps per chunk

typedef float f32x4 __attribute__((ext_vector_type(4)));
typedef short bf16x8 __attribute__((ext_vector_type(8)));
typedef unsigned short u16x4 __attribute__((ext_vector_type(4)));

__device__ __forceinline__ float b2f(unsigned short s){
  union { float f; unsigned u; } z; z.u = ((unsigned)s) << 16; return z.f;
}
__device__ __forceinline__ unsigned short f2b(float f){
  union { float f; unsigned u; } z; z.f = f;
  unsigned u = z.u;
  u += 0x7fffu + ((u >> 16) & 1u);   // round-to-nearest-even
  return (unsigned short)(u >> 16);
}
__device__ __forceinline__ float sigmoidf_(float v){
  return 1.0f / (1.0f + __expf(-v));
}
__device__ __forceinline__ void gld_lds16(const void* g, void* l){
  __builtin_amdgcn_global_load_lds((const __attribute__((address_space(1))) unsigned int*)g,
                                   (__attribute__((address_space(3))) unsigned int*)l,
                                   16, 0, 0);
}

// XCD-chunked swizzle for 256-block 256^2 GEMM grid (64 m-panels x 4 n-panels).
// 4 consecutive blocks per XCD share one m-panel (A-panel 512KB L2-hot);
// per-XCD B working set 4x512KB = 2MB resident. [T1]
__device__ __forceinline__ void swz256(int bid, int& m0, int& n0){
  int xcd = bid & 7;
  int loc = bid >> 3;              // 0..31
  int wg  = xcd*32 + loc;
  m0 = (wg >> 2) * 256;
  n0 = (wg & 3) * 256;
}

// ---------------- weight convert fp32 -> bf16 ----------------
__global__ __launch_bounds__(256) void wconv_kernel(const float* __restrict__ W0, const float* __restrict__ W1,
                                                    const float* __restrict__ W2, const float* __restrict__ W3,
                                                    unsigned short* __restrict__ WC){
  int mat = blockIdx.y;
  const float* src = (mat==0) ? W0 : (mat==1) ? W1 : (mat==2) ? W2 : W3;
  size_t i = ((size_t)blockIdx.x*256 + threadIdx.x)*4;
  f32x4 v = *(const f32x4*)(src + i);
  u16x4 o; o[0]=f2b(v[0]); o[1]=f2b(v[1]); o[2]=f2b(v[2]); o[3]=f2b(v[3]);
  *(u16x4*)(WC + (size_t)mat*1048576 + i) = o;
}

// ---------------- fused LayerNorm + time-mix -> xk, xv, xr (bf16) ----------------
__global__ __launch_bounds__(256) void lnmix_kernel(const float* __restrict__ x,
                                                    const float* __restrict__ lnw, const float* __restrict__ lnb,
                                                    const float* __restrict__ tmk, const float* __restrict__ tmv,
                                                    const float* __restrict__ tmr,
                                                    unsigned short* __restrict__ XK, unsigned short* __restrict__ XV,
                                                    unsigned short* __restrict__ XR){
  int m = blockIdx.x;
  int tid = threadIdx.x;
  bool first = (m & (SEQ-1)) == 0;
  size_t base = (size_t)m*D_MODEL + tid*4;
  f32x4 xc = *(const f32x4*)(x + base);
  f32x4 xp = {0.f,0.f,0.f,0.f};
  if (!first) xp = *(const f32x4*)(x + base - D_MODEL);

  float c1 = xc[0]+xc[1]+xc[2]+xc[3];
  float c2 = xc[0]*xc[0]+xc[1]*xc[1]+xc[2]*xc[2]+xc[3]*xc[3];
  float p1 = xp[0]+xp[1]+xp[2]+xp[3];
  float p2 = xp[0]*xp[0]+xp[1]*xp[1]+xp[2]*xp[2]+xp[3]*xp[3];
  #pragma unroll
  for (int off = 32; off > 0; off >>= 1){
    c1 += __shfl_xor(c1, off); c2 += __shfl_xor(c2, off);
    p1 += __shfl_xor(p1, off); p2 += __shfl_xor(p2, off);
  }
  __shared__ float rc1[4], rc2[4], rp1[4], rp2[4];
  int w = tid >> 6, lane = tid & 63;
  if (lane == 0){ rc1[w]=c1; rc2[w]=c2; rp1[w]=p1; rp2[w]=p2; }
  __syncthreads();
  c1 = rc1[0]+rc1[1]+rc1[2]+rc1[3];
  c2 = rc2[0]+rc2[1]+rc2[2]+rc2[3];
  p1 = rp1[0]+rp1[1]+rp1[2]+rp1[3];
  p2 = rp2[0]+rp2[1]+rp2[2]+rp2[3];
  float mC = c1*(1.0f/1024.0f), vC = c2*(1.0f/1024.0f)-mC*mC, rC = rsqrtf(vC+1e-5f);
  float mP = p1*(1.0f/1024.0f), vP = p2*(1.0f/1024.0f)-mP*mP, rP = rsqrtf(vP+1e-5f);

  f32x4 wv = *(const f32x4*)(lnw + tid*4);
  f32x4 bv = *(const f32x4*)(lnb + tid*4);
  f32x4 k4 = *(const f32x4*)(tmk + tid*4);
  f32x4 v4 = *(const f32x4*)(tmv + tid*4);
  f32x4 r4 = *(const f32x4*)(tmr + tid*4);
  u16x4 ok, ov, orr;
  #pragma unroll
  for (int j=0;j<4;j++){
    float nc = (xc[j]-mC)*rC*wv[j] + bv[j];
    float np = first ? 0.f : (xp[j]-mP)*rP*wv[j] + bv[j];
    ok[j]  = f2b(np + k4[j]*(nc-np));
    ov[j]  = f2b(np + v4[j]*(nc-np));
    orr[j] = f2b(np + r4[j]*(nc-np));
  }
  *(u16x4*)(XK + base) = ok;
  *(u16x4*)(XV + base) = ov;
  *(u16x4*)(XR + base) = orr;
}

// ---------------- 256x256 GEMM core: BK=64, 8 waves (2m x 4n), dbuf LDS,
// 1-K-tile-deep prefetch with counted drain (loads in flight across raw barriers),
// setprio around MFMA clusters. LDS 128 KiB. ----------------
__device__ __forceinline__ void gemm256_core(const unsigned short* __restrict__ A,
                                             const unsigned short* __restrict__ W,
                                             int m0, int n0, int tid,
                                             unsigned short* As, unsigned short* Bs,
                                             f32x4 (&acc)[8][4]){
  int wid = tid >> 6, lane = tid & 63;
  int wm = wid >> 2, wn = wid & 3;        // 2 x 4 waves, wave tile 128x64
  int fr = lane & 15, fg = lane >> 4;

  // per-thread staging offsets: 4 chunk-loads per operand per K-tile.
  // source pre-swizzled so LDS stays linear (gld_lds requirement) while
  // reads use the XOR-swizzled address (both-sides rule, m201/m231).
  int offAg[4], offBg[4], offL[4];
  #pragma unroll
  for (int it = 0; it < 4; ++it){
    int chunk = it*512 + tid;          // 0..2047
    int row = chunk >> 3;              // 0..255
    int cg = (chunk & 7) ^ (row & 7);
    offAg[it] = (m0+row)*D_MODEL + cg*8;
    offBg[it] = (n0+row)*D_MODEL + cg*8;
    offL[it]  = chunk*8;
  }

  #define STAGE256(bsel, kt) { \
    _Pragma("unroll") \
    for (int it = 0; it < 4; ++it){ \
      gld_lds16(A + offAg[it] + (kt)*64, &As[(bsel)*16384 + offL[it]]); \
      gld_lds16(W + offBg[it] + (kt)*64, &Bs[(bsel)*16384 + offL[it]]); \
    } }

  STAGE256(0, 0);
  for (int kt = 0; kt < 16; ++kt){
    int cur = kt & 1;
    // tile kt's 8 loads were issued one full K-tile of compute ago
    asm volatile("s_waitcnt vmcnt(0)" ::: "memory");
    __builtin_amdgcn_s_barrier();
    if (kt < 15) STAGE256(cur^1, kt+1);   // stays in flight across the phase barriers below
    const unsigned short* Ab = &As[cur*16384];
    const unsigned short* Bb = &Bs[cur*16384];
    #pragma unroll
    for (int ks = 0; ks < 2; ++ks){
      bf16x8 a[8], b[4];
      #pragma unroll
      for (int mi=0; mi<8; ++mi){
        int r = wm*128 + mi*16 + fr;
        a[mi] = *(const bf16x8*)(&Ab[r*64 + (((ks*4+fg) ^ (r&7))<<3)]);
      }
      #pragma unroll
      for (int ni=0; ni<4; ++ni){
        int r = wn*64 + ni*16 + fr;
        b[ni] = *(const bf16x8*)(&Bb[r*64 + (((ks*4+fg) ^ (r&7))<<3)]);
      }
      __builtin_amdgcn_s_setprio(1);
      #pragma unroll
      for (int mi=0; mi<8; ++mi)
        #pragma unroll
        for (int ni=0; ni<4; ++ni)
          acc[mi][ni] = __builtin_amdgcn_mfma_f32_16x16x32_bf16(a[mi], b[ni], acc[mi][ni], 0, 0, 0);
      __builtin_amdgcn_s_setprio(0);
      __builtin_amdgcn_s_barrier();
    }
  }
  #undef STAGE256
}

// ---------------- merged mix GEMMs: z=0 k->KB, z=1 v->VB, z=2 sigmoid r->RB ----------------
__global__ __launch_bounds__(512) void gemm_mix3_kernel(const unsigned short* __restrict__ XK,
                                                        const unsigned short* __restrict__ XV,
                                                        const unsigned short* __restrict__ XR,
                                                        const unsigned short* __restrict__ WC,
                                                        unsigned short* __restrict__ KB,
                                                        unsigned short* __restrict__ VB,
                                                        unsigned short* __restrict__ RB){
  __shared__ alignas(16) unsigned short As[2*16384];
  __shared__ alignas(16) unsigned short Bs[2*16384];
  int m0, n0; swz256(blockIdx.x, m0, n0);
  int z = blockIdx.z;
  int tid = threadIdx.x;
  const unsigned short* A = (z==0) ? XK : (z==1) ? XV : XR;
  const unsigned short* W = WC + (size_t)z*1048576;
  unsigned short* O       = (z==0) ? KB : (z==1) ? VB : RB;

  f32x4 acc[8][4];
  #pragma unroll
  for (int i=0;i<8;i++)
    #pragma unroll
    for (int j=0;j<4;j++){ acc[i][j][0]=0.f; acc[i][j][1]=0.f; acc[i][j][2]=0.f; acc[i][j][3]=0.f; }

  gemm256_core(A, W, m0, n0, tid, As, Bs, acc);

  int wid = tid >> 6, lane = tid & 63;
  int wm = wid >> 2, wn = wid & 3;
  int fr = lane & 15, fg = lane >> 4;
  #pragma unroll
  for (int mi=0; mi<8; ++mi){
    #pragma unroll
    for (int ni=0; ni<4; ++ni){
      int c = n0 + wn*64 + ni*16 + fr;
      #pragma unroll
      for (int j=0; j<4; ++j){
        int r = m0 + wm*128 + mi*16 + fg*4 + j;
        size_t idx = (size_t)r*D_MODEL + c;
        float val = acc[mi][ni][j];
        if (z == 2) val = sigmoidf_(val);
        O[idx] = f2b(val);
      }
    }
  }
}

// ---------------- out GEMM: o = S_seq @ Wo^T ; out = x + r*o ----------------
__global__ __launch_bounds__(512) void gemm_out_kernel(const unsigned short* __restrict__ Sb,
                                                       const unsigned short* __restrict__ Wo,
                                                       const float* __restrict__ x,
                                                       const unsigned short* __restrict__ RB,
                                                       float* __restrict__ out){
  __shared__ alignas(16) unsigned short As[2*16384];
  __shared__ alignas(16) unsigned short Bs[2*16384];
  int m0, n0; swz256(blockIdx.x, m0, n0);
  int tid = threadIdx.x;

  f32x4 acc[8][4];
  #pragma unroll
  for (int i=0;i<8;i++)
    #pragma unroll
    for (int j=0;j<4;j++){ acc[i][j][0]=0.f; acc[i][j][1]=0.f; acc[i][j][2]=0.f; acc[i][j][3]=0.f; }

  gemm256_core(Sb, Wo, m0, n0, tid, As, Bs, acc);

  int wid = tid >> 6, lane = tid & 63;
  int wm = wid >> 2, wn = wid & 3;
  int fr = lane & 15, fg = lane >> 4;
  #pragma unroll
  for (int mi=0; mi<8; ++mi){
    #pragma unroll
    for (int ni=0; ni<4; ++ni){
      int c = n0 + wn*64 + ni*16 + fr;
      #pragma unroll
      for (int j=0; j<4; ++j){
        int r = m0 + wm*128 + mi*16 + fg*4 + j;
        size_t idx = (size_t)r*D_MODEL + c;
        float rr = b2f(RB[idx]);
        out[idx] = x[idx] + rr * acc[mi][ni][j];
      }
    }
  }
}

// ---------------- scan phase 1: per-chunk carries (kv = k*v on the fly) ----------------
__global__ __launch_bounds__(256) void scan_p1_kernel(const unsigned short* __restrict__ kb,
                                                      const unsigned short* __restrict__ vb,
                                                      const float* __restrict__ dw,
                                                      float* __restrict__ carr){
  int bc = blockIdx.x;            // b*NC + c
  int b = bc >> 6, c = bc & (NC-1);
  int d0 = threadIdx.x * 4;
  float dx = sigmoidf_(dw[d0+0]);
  float dy = sigmoidf_(dw[d0+1]);
  float dz = sigmoidf_(dw[d0+2]);
  float dwv = sigmoidf_(dw[d0+3]);
  float Sx=0.f, Sy=0.f, Sz=0.f, Sw=0.f;
  size_t base = ((size_t)(b*SEQ + c*CL))*D_MODEL + d0;
  for (int i=0;i<CL;i++){
    u16x4 k4 = *(const u16x4*)(kb + base);
    u16x4 v4 = *(const u16x4*)(vb + base);
    Sx = dx*Sx + b2f(k4[0])*b2f(v4[0]);
    Sy = dy*Sy + b2f(k4[1])*b2f(v4[1]);
    Sz = dz*Sz + b2f(k4[2])*b2f(v4[2]);
    Sw = dwv*Sw + b2f(k4[3])*b2f(v4[3]);
    base += D_MODEL;
  }
  f32x4 o; o[0]=Sx; o[1]=Sy; o[2]=Sz; o[3]=Sw;
  *(f32x4*)(carr + (size_t)bc*D_MODEL + d0) = o;
}

// ---------------- scan phase 2: cross-chunk exclusive scan (in-place) ----------------
__global__ __launch_bounds__(256) void scan_p2_kernel(const float* __restrict__ dw, float* __restrict__ carr){
  int gid = blockIdx.x*256 + threadIdx.x;   // 0..8191
  int b = gid >> 10, d = gid & (D_MODEL-1);
  float dec = sigmoidf_(dw[d]);
  float dL = dec;
  #pragma unroll
  for (int i=0;i<5;i++) dL *= dL;           // dec^32
  float S = 0.f;
  for (int c=0;c<NC;c++){
    size_t idx = ((size_t)(b*NC + c))*D_MODEL + d;
    float cr = carr[idx];
    carr[idx] = S;                          // becomes carry-in
    S = dL*S + cr;
  }
}

// ---------------- scan phase 3: prefix with carry-in; write S_seq fp32 + bf16 in-place over V ----------------
__global__ __launch_bounds__(256) void scan_p3_kernel(const unsigned short* __restrict__ kb,
                                                      unsigned short* vsb,   // v in, S bf16 out (same buffer, same element)
                                                      const float* __restrict__ dw,
                                                      const float* __restrict__ cin,
                                                      float* __restrict__ sseq,
                                                      float* __restrict__ finalS){
  int bc = blockIdx.x;
  int b = bc >> 6, c = bc & (NC-1);
  int d0 = threadIdx.x * 4;
  float dx = sigmoidf_(dw[d0+0]);
  float dy = sigmoidf_(dw[d0+1]);
  float dz = sigmoidf_(dw[d0+2]);
  float dwv = sigmoidf_(dw[d0+3]);
  f32x4 S = *(const f32x4*)(cin + (size_t)bc*D_MODEL + d0);
  size_t base = ((size_t)(b*SEQ + c*CL))*D_MODEL + d0;
  for (int i=0;i<CL;i++){
    u16x4 k4 = *(const u16x4*)(kb + base);
    u16x4 v4 = *(const u16x4*)(vsb + base);
    S[0] = dx*S[0] + b2f(k4[0])*b2f(v4[0]);
    S[1] = dy*S[1] + b2f(k4[1])*b2f(v4[1]);
    S[2] = dz*S[2] + b2f(k4[2])*b2f(v4[2]);
    S[3] = dwv*S[3] + b2f(k4[3])*b2f(v4[3]);
    *(f32x4*)(sseq + base) = S;
    u16x4 s4; s4[0]=f2b(S[0]); s4[1]=f2b(S[1]); s4[2]=f2b(S[2]); s4[3]=f2b(S[3]);
    *(u16x4*)(vsb + base) = s4;
    base += D_MODEL;
  }
  if (c == NC-1)
    *(f32x4*)(finalS + (size_t)b*D_MODEL + d0) = S;
}

extern "C" void kernel_launch(void* const* d_in, const int* in_sizes, int n_in,
                              void* d_out, int out_size, void* d_ws, size_t ws_size,
                              hipStream_t stream){
  const float* x   = (const float*)d_in[0];
  const float* lnw = (const float*)d_in[1];
  const float* lnb = (const float*)d_in[2];
  const float* tmk = (const float*)d_in[3];
  const float* tmv = (const float*)d_in[4];
  const float* tmr = (const float*)d_in[5];
  const float* dw  = (const float*)d_in[6];
  const float* Wk  = (const float*)d_in[7];
  const float* Wv  = (const float*)d_in[8];
  const float* Wr  = (const float*)d_in[9];
  const float* Wo  = (const float*)d_in[10];

  float* out    = (float*)d_out;
  float* finalS = out + (size_t)M_TOTAL*D_MODEL;
  float* sseq   = finalS + (size_t)BATCH*D_MODEL;

  // d_out doubles as GEMM-phase scratch:
  //   XK = out[0 .. 33.5MB)           dead before gemm_out writes out
  //   XV = out[33.5MB .. 67.1MB)      dead before gemm_out writes out
  //   XR = sseq region (first 33.5MB) dead before scan_p3 writes sseq
  unsigned short* XK = (unsigned short*)d_out;
  unsigned short* XV = (unsigned short*)((char*)d_out + 33554432);
  unsigned short* XR = (unsigned short*)sseq;

  char* w = (char*)d_ws;
  unsigned short* WC   = (unsigned short*)(w + 0);           // 8.4 MB (Wk,Wv,Wr,Wo bf16)
  unsigned short* VSB  = (unsigned short*)(w + 8388608);     // 33.5 MB: v, then S bf16 (in-place)
  unsigned short* KB   = (unsigned short*)(w + 41943040);    // 33.5 MB: k
  unsigned short* RB   = (unsigned short*)(w + 75497472);    // 33.5 MB: r = sigmoid(xr@Wr^T)
  float*          CARR = (float*)(w + 109051904);            // 2 MB carries (in-place -> carry-in)

  wconv_kernel<<<dim3(1024,4), 256, 0, stream>>>(Wk, Wv, Wr, Wo, WC);
  lnmix_kernel<<<M_TOTAL, 256, 0, stream>>>(x, lnw, lnb, tmk, tmv, tmr, XK, XV, XR);

  gemm_mix3_kernel<<<dim3(256,1,3), 512, 0, stream>>>(XK, XV, XR, WC, KB, VSB, RB);

  scan_p1_kernel<<<BATCH*NC, 256, 0, stream>>>(KB, VSB, dw, CARR);
  scan_p2_kernel<<<32, 256, 0, stream>>>(dw, CARR);
  scan_p3_kernel<<<BATCH*NC, 256, 0, stream>>>(KB, VSB, dw, CARR, sseq, finalS);

  gemm_out_kernel<<<256, 512, 0, stream>>>(VSB, WC + (size_t)3*1048576, x, RB, out);
}